// Round 13
// baseline (105.139 us; speedup 1.0000x reference)
//
#include <hip/hip_runtime.h>

#define MD    4
#define B_    4
#define C_    128
#define H_    128
#define W_    256
#define ND    9            // 2*MD+1 displacements per axis
#define XPT   4            // x pixels per lane (64 lanes cover W)
#define CHALF (C_ / 2)     // channels per wave

typedef float float4v __attribute__((ext_vector_type(4)));

// Occupancy experiment: R4's exact body (XPT=4, shuffle halo), but each
// wave does HALF the channels; 2-wave blocks (ch-half 0/1) reduce via one
// 9KB LDS buffer + single barrier. 4608 blocks x 128thr -> 18 blocks/CU;
// VGPR capped at 64 -> 32 waves/CU resident (vs 18 in R4, 9 in R9-R12).
// Per-CU L1 bytes / DS ops / FMAs identical to R4 -- pure TLP change.
__global__ __launch_bounds__(128, 8)   // 8 waves/EU -> 16 blocks, VGPR <= 64
void corr_kernel(const float* __restrict__ t1,
                 const float* __restrict__ t2,
                 float* __restrict__ out) {
    __shared__ __align__(16) float pacc[ND][W_];   // 9216 B

    const int tid  = threadIdx.x;
    const int lane = tid & 63;
    const int chh  = tid >> 6;              // 0: ch 0-63, 1: ch 64-127
    const int bid  = blockIdx.x;            // 4608 = 8 XCDs * 576
    const int swz  = (bid & 7) * 576 + (bid >> 3);
    const int by   = swz / ND;              // b*128 + y  (y-contig per XCD)
    const int dy   = swz - by * ND;         // 0..8
    const int b    = by >> 7;
    const int y    = by & 127;
    const int x0   = lane * XPT;            // 0..252
    const int yy   = y + dy - MD;           // shifted t2 row (may be OOB)
    const bool live = (0 <= yy) && (yy < H_);
    const bool lm  = (lane == 0);           // left halo is pad-zero
    const bool rm  = (lane == 63);          // right halo is pad-zero

    float acc[ND][XPT];
    #pragma unroll
    for (int dx = 0; dx < ND; ++dx)
        #pragma unroll
        for (int j = 0; j < XPT; ++j) acc[dx][j] = 0.0f;

    if (live) {
        const float* p1 =
            t1 + (((size_t)(b * C_ + chh * CHALF)) * H_ + y ) * W_ + x0;
        const float* p2 =
            t2 + (((size_t)(b * C_ + chh * CHALF)) * H_ + yy) * W_ + x0;
        const size_t chstr = (size_t)H_ * W_;

        #pragma unroll 2
        for (int c = 0; c < CHALF; ++c) {
            const float4v a = *(const float4v*)(p1 + (size_t)c * chstr);
            const float4v v = *(const float4v*)(p2 + (size_t)c * chstr);

            // win[k] = t2 at x = x0 - 4 + k, k = 0..11
            float win[XPT + 2 * MD];
            #pragma unroll
            for (int k = 0; k < 4; ++k) {
                const float up = __shfl_up(v[k], 1);
                const float dn = __shfl_down(v[k], 1);
                win[k]     = lm ? 0.0f : up;
                win[4 + k] = v[k];
                win[8 + k] = rm ? 0.0f : dn;
            }

            #pragma unroll
            for (int dx = 0; dx < ND; ++dx)
                #pragma unroll
                for (int j = 0; j < XPT; ++j)
                    acc[dx][j] = fmaf(a[j], win[dx + j], acc[dx][j]);
        }
    }
    // !live: acc stays 0 in both waves -> zeros stored (matches zero-pad)

    if (chh == 0) {                         // wave 0: park partials in LDS
        #pragma unroll
        for (int dx = 0; dx < ND; ++dx) {
            float4v o;
            #pragma unroll
            for (int j = 0; j < XPT; ++j) o[j] = acc[dx][j];
            *(float4v*)&pacc[dx][x0] = o;
        }
    }
    __syncthreads();
    if (chh == 1) {                         // wave 1: combine + store
        const float scale = 1.0f / (float)C_;
        #pragma unroll
        for (int dx = 0; dx < ND; ++dx) {
            const float4v p = *(const float4v*)&pacc[dx][x0];
            float4v o;
            #pragma unroll
            for (int j = 0; j < XPT; ++j)
                o[j] = (acc[dx][j] + p[j]) * scale;
            const size_t oidx =
                (((size_t)(b * ND * ND) + dy * ND + dx) * H_ + y) * W_ + x0;
            *(float4v*)&out[oidx] = o;
        }
    }
}

extern "C" void kernel_launch(void* const* d_in, const int* in_sizes, int n_in,
                              void* d_out, int out_size, void* d_ws, size_t ws_size,
                              hipStream_t stream) {
    const float* t1 = (const float*)d_in[0];
    const float* t2 = (const float*)d_in[1];
    float* out      = (float*)d_out;
    corr_kernel<<<dim3(B_ * H_ * ND), 128, 0, stream>>>(t1, t2, out);
}

// Round 14
// 77.433 us; speedup vs baseline: 1.3578x; 1.3578x over previous
//
#include <hip/hip_runtime.h>

#define MD    4
#define B_    4
#define C_    128
#define H_    128
#define W_    256
#define ND    9            // 2*MD+1 displacements per axis
#define XPT   4            // x pixels per lane (64 lanes cover W)
#define CHALF (C_ / 2)     // channels per wave

typedef float float4v __attribute__((ext_vector_type(4)));

// R13 occupancy experiment, un-confounded: launch_bounds(128,6) caps VGPR
// at 85 (R13's (128,8) capped at 64 < ~70 live -> acc spilled to scratch,
// VGPR_Count 32, WRITE +9MB, slower). 6 waves/SIMD = 24 waves/CU resident
// vs R4's 14; per-CU L1 bytes / DS ops / FMAs identical. Pure TLP change.
__global__ __launch_bounds__(128, 6)
void corr_kernel(const float* __restrict__ t1,
                 const float* __restrict__ t2,
                 float* __restrict__ out) {
    __shared__ __align__(16) float pacc[ND][W_];   // 9216 B

    const int tid  = threadIdx.x;
    const int lane = tid & 63;
    const int chh  = tid >> 6;              // 0: ch 0-63, 1: ch 64-127
    const int bid  = blockIdx.x;            // 4608 = 8 XCDs * 576
    const int swz  = (bid & 7) * 576 + (bid >> 3);
    const int by   = swz / ND;              // b*128 + y  (y-contig per XCD)
    const int dy   = swz - by * ND;         // 0..8
    const int b    = by >> 7;
    const int y    = by & 127;
    const int x0   = lane * XPT;            // 0..252
    const int yy   = y + dy - MD;           // shifted t2 row (may be OOB)
    const bool live = (0 <= yy) && (yy < H_);
    const bool lm  = (lane == 0);           // left halo is pad-zero
    const bool rm  = (lane == 63);          // right halo is pad-zero

    float acc[ND][XPT];
    #pragma unroll
    for (int dx = 0; dx < ND; ++dx)
        #pragma unroll
        for (int j = 0; j < XPT; ++j) acc[dx][j] = 0.0f;

    if (live) {
        const float* p1 =
            t1 + (((size_t)(b * C_ + chh * CHALF)) * H_ + y ) * W_ + x0;
        const float* p2 =
            t2 + (((size_t)(b * C_ + chh * CHALF)) * H_ + yy) * W_ + x0;
        const size_t chstr = (size_t)H_ * W_;

        #pragma unroll 2
        for (int c = 0; c < CHALF; ++c) {
            const float4v a = *(const float4v*)(p1 + (size_t)c * chstr);
            const float4v v = *(const float4v*)(p2 + (size_t)c * chstr);

            // win[k] = t2 at x = x0 - 4 + k, k = 0..11
            float win[XPT + 2 * MD];
            #pragma unroll
            for (int k = 0; k < 4; ++k) {
                const float up = __shfl_up(v[k], 1);
                const float dn = __shfl_down(v[k], 1);
                win[k]     = lm ? 0.0f : up;
                win[4 + k] = v[k];
                win[8 + k] = rm ? 0.0f : dn;
            }

            #pragma unroll
            for (int dx = 0; dx < ND; ++dx)
                #pragma unroll
                for (int j = 0; j < XPT; ++j)
                    acc[dx][j] = fmaf(a[j], win[dx + j], acc[dx][j]);
        }
    }
    // !live: acc stays 0 in both waves -> zeros stored (matches zero-pad)

    if (chh == 0) {                         // wave 0: park partials in LDS
        #pragma unroll
        for (int dx = 0; dx < ND; ++dx) {
            float4v o;
            #pragma unroll
            for (int j = 0; j < XPT; ++j) o[j] = acc[dx][j];
            *(float4v*)&pacc[dx][x0] = o;
        }
    }
    __syncthreads();
    if (chh == 1) {                         // wave 1: combine + store
        const float scale = 1.0f / (float)C_;
        #pragma unroll
        for (int dx = 0; dx < ND; ++dx) {
            const float4v p = *(const float4v*)&pacc[dx][x0];
            float4v o;
            #pragma unroll
            for (int j = 0; j < XPT; ++j)
                o[j] = (acc[dx][j] + p[j]) * scale;
            const size_t oidx =
                (((size_t)(b * ND * ND) + dy * ND + dx) * H_ + y) * W_ + x0;
            *(float4v*)&out[oidx] = o;
        }
    }
}

extern "C" void kernel_launch(void* const* d_in, const int* in_sizes, int n_in,
                              void* d_out, int out_size, void* d_ws, size_t ws_size,
                              hipStream_t stream) {
    const float* t1 = (const float*)d_in[0];
    const float* t2 = (const float*)d_in[1];
    float* out      = (float*)d_out;
    corr_kernel<<<dim3(B_ * H_ * ND), 128, 0, stream>>>(t1, t2, out);
}